// Round 2
// baseline (389.585 us; speedup 1.0000x reference)
//
#include <hip/hip_runtime.h>
#include <stdint.h>

// BinaryConv2D: x (64,56,56,128) NHWC fp32, w (3,3,128,256) HWIO fp32.
// binarize(v) = v>=0 ? +1 : -1 (bit = 1 iff v < 0). SAME pad: pad taps give 0.
// dot = 128*Nvalid - 2*(popcAll - sum_{invalid taps} popc(w_tap))  with
// zero-filled LDS for pad columns / out-of-range rows.

#define IH 56
#define IW 56
#define CIN 128
#define COUT 256
#define NB 64

// ---- pack w -> wp[(tap*2+half)*256 + oc], bit i = channel half*64+i ----
__global__ void pack_w_kernel(const float* __restrict__ w,
                              uint64_t* __restrict__ wp) {
    int gtid = blockIdx.x * blockDim.x + threadIdx.x;
    int wave = gtid >> 6, lane = gtid & 63;
    int nw = (gridDim.x * blockDim.x) >> 6;
    const int ntask = 9 * 2 * COUT;
    for (int t = wave; t < ntask; t += nw) {
        int oc = t & 255, hf = (t >> 8) & 1, tap = t >> 9;
        float v = w[((size_t)(tap * CIN + hf * 64 + lane)) * COUT + oc];
        uint64_t m = __ballot(v < 0.0f);
        if (lane == 0) wp[(size_t)(tap * 2 + hf) * COUT + oc] = m;
    }
}

__device__ __forceinline__ int popc9(const uint64_t X[3][2], const uint64_t Y[3][2],
                                     const uint64_t Z[3][2], const uint64_t wr[9][2]) {
    int s = 0;
#pragma unroll
    for (int kh = 0; kh < 3; ++kh) {
        s += __popcll(X[kh][0] ^ wr[kh * 3 + 0][0]) + __popcll(X[kh][1] ^ wr[kh * 3 + 0][1]);
        s += __popcll(Y[kh][0] ^ wr[kh * 3 + 1][0]) + __popcll(Y[kh][1] ^ wr[kh * 3 + 1][1]);
        s += __popcll(Z[kh][0] ^ wr[kh * 3 + 2][0]) + __popcll(Z[kh][1] ^ wr[kh * 3 + 2][1]);
    }
    return s;
}

#define LOADCOL(dst, rb, cc)                                    \
    do {                                                        \
        _Pragma("unroll")                                       \
        for (int _k = 0; _k < 3; ++_k) {                        \
            dst[_k][0] = xs[(rb) + _k][(cc)][0];                \
            dst[_k][1] = xs[(rb) + _k][(cc)][1];                \
        }                                                       \
    } while (0)

// block = (n, h-pair), thread = oc; binarize fused; 2 output rows per block
__global__ __launch_bounds__(256, 4) void bconv_kernel(
        const float* __restrict__ x,
        const uint64_t* __restrict__ wp,
        float* __restrict__ out) {
    __shared__ alignas(16) uint64_t xs[4][58][2];  // rows h0-1..h0+2, cols -1..56

    int bh = blockIdx.x % 28;
    int n  = blockIdx.x / 28;
    int h0 = bh * 2;
    int tid = threadIdx.x, oc = tid;
    int wv = tid >> 6, lane = tid & 63;

    // filter: 9 taps x 128 bits, coalesced u64 loads (lane-consecutive)
    uint64_t wr[9][2];
#pragma unroll
    for (int t = 0; t < 9; ++t) {
        wr[t][0] = wp[(size_t)(t * 2 + 0) * COUT + oc];
        wr[t][1] = wp[(size_t)(t * 2 + 1) * COUT + oc];
    }

    // zero-fill LDS (pad cols + invalid rows must be 0)
    uint64_t* xf = &xs[0][0][0];
    for (int i = tid; i < 4 * 58 * 2; i += 256) xf[i] = 0;
    __syncthreads();

    // stage 4 binarized rows via ballot (one wave-task per pixel)
    for (int task = wv; task < 4 * IW; task += 4) {
        int kh = task / IW, col = task % IW;
        int r = h0 - 1 + kh;
        if ((unsigned)r < IH) {
            const float* px = x + (((size_t)n * IH + r) * IW + col) * CIN;
            float a = px[lane];
            float b = px[64 + lane];
            uint64_t m0 = __ballot(a < 0.0f);
            uint64_t m1 = __ballot(b < 0.0f);
            if (lane == 0) { xs[kh][col + 1][0] = m0; xs[kh][col + 1][1] = m1; }
        }
    }
    __syncthreads();

    // per-tap popcounts of w for edge corrections
    int pcw[9];
#pragma unroll
    for (int t = 0; t < 9; ++t) pcw[t] = __popcll(wr[t][0]) + __popcll(wr[t][1]);
    int rs0 = pcw[0] + pcw[1] + pcw[2];           // window-row 0 sum
    int rs2 = pcw[6] + pcw[7] + pcw[8];           // window-row 2 sum
    int cs0 = pcw[0] + pcw[3] + pcw[6];           // kw=0 col sum
    int cs2 = pcw[2] + pcw[5] + pcw[8];           // kw=2 col sum

    // row A = h0 (xs rows 0..2): window-row 0 invalid iff h0==0
    bool eA = (h0 == 0);
    int vhA = eA ? 2 : 3, invA = eA ? rs0 : 0;
    int c0A = eA ? pcw[0] : 0, c2A = eA ? pcw[2] : 0;
    int KintA = 384 * vhA + 2 * invA;
    int K0A = 256 * vhA + 2 * (invA + cs0 - c0A);
    int K55A = 256 * vhA + 2 * (invA + cs2 - c2A);

    // row B = h0+1 (xs rows 1..3): window-row 2 invalid iff h0+1==55
    bool eB = (h0 + 1 == IH - 1);
    int vhB = eB ? 2 : 3, invB = eB ? rs2 : 0;
    int c0B = eB ? pcw[6] : 0, c2B = eB ? pcw[8] : 0;
    int KintB = 384 * vhB + 2 * invB;
    int K0B = 256 * vhB + 2 * (invB + cs0 - c0B);
    int K55B = 256 * vhB + 2 * (invB + cs2 - c2B);

    auto conv_row = [&](int rb, int K0, int Kint, int K55, float* po) {
        uint64_t A[3][2], B[3][2], C[3][2];
        LOADCOL(A, rb, 0);
        LOADCOL(B, rb, 1);
        // w=0
        LOADCOL(C, rb, 2);
        po[0] = (float)(K0 - 2 * popc9(A, B, C, wr)); po += COUT;
        // w=1
        LOADCOL(A, rb, 3);
        po[0] = (float)(Kint - 2 * popc9(B, C, A, wr)); po += COUT;
        // w=2..55, rotation period 3, 18 iterations
        for (int wb = 2; wb <= 53; wb += 3) {
            LOADCOL(B, rb, wb + 2);
            po[0] = (float)(Kint - 2 * popc9(C, A, B, wr)); po += COUT;
            LOADCOL(C, rb, wb + 3);
            po[0] = (float)(Kint - 2 * popc9(A, B, C, wr)); po += COUT;
            LOADCOL(A, rb, wb + 4);
            int k = (wb == 53) ? K55 : Kint;
            po[0] = (float)(k - 2 * popc9(B, C, A, wr)); po += COUT;
        }
    };

    float* poA = out + (((size_t)n * IH + h0) * IW) * COUT + oc;
    conv_row(0, K0A, KintA, K55A, poA);
    conv_row(1, K0B, KintB, K55B, poA + (size_t)IW * COUT);
}

extern "C" void kernel_launch(void* const* d_in, const int* in_sizes, int n_in,
                              void* d_out, int out_size, void* d_ws, size_t ws_size,
                              hipStream_t stream) {
    const float* x = (const float*)d_in[0];
    const float* w = (const float*)d_in[1];
    float* out = (float*)d_out;
    uint64_t* wp = (uint64_t*)d_ws;   // 4608 u64 = 36 KB

    pack_w_kernel<<<288, 256, 0, stream>>>(w, wp);         // 1152 waves, 4 tasks each
    bconv_kernel<<<NB * 28, 256, 0, stream>>>(x, wp, out); // 1792 blocks
}

// Round 3
// 369.658 us; speedup vs baseline: 1.0539x; 1.0539x over previous
//
#include <hip/hip_runtime.h>
#include <stdint.h>

// BinaryConv2D: x (64,56,56,128) NHWC fp32, w (3,3,128,256) HWIO fp32.
// binarize(v) = v>=0 ? +1 : -1 (bit=1 iff v<0). dot = K_valid - 2*popc(x^w),
// pad taps excluded via zero-filled x-bits + per-tap w-popcount corrections.
// Bit mapping (must match between pack_x and pack_w):
//   word0 bit l = channel 2l, word1 bit l = channel 2l+1.

#define IH 56
#define IW 56
#define CIN 128
#define COUT 256
#define NB 64

// ---- pack x: one wave per pixel, float2 loads, ballot ----
__global__ void pack_x_kernel(const float* __restrict__ x,
                              uint64_t* __restrict__ xp, int npix) {
    int gtid = blockIdx.x * blockDim.x + threadIdx.x;
    int wave = gtid >> 6, lane = gtid & 63;
    int nw = (gridDim.x * blockDim.x) >> 6;
    const float2* x2 = (const float2*)x;
    for (int p = wave; p < npix; p += nw) {
        float2 v = x2[(size_t)p * 64 + lane];   // channels 2l, 2l+1
        uint64_t m0 = __ballot(v.x < 0.0f);
        uint64_t m1 = __ballot(v.y < 0.0f);
        if (lane == 0) { xp[2 * (size_t)p] = m0; xp[2 * (size_t)p + 1] = m1; }
    }
}

// ---- pack w -> wp[(tap*2+hf)*256 + oc]; bit l = channel 2l+hf ----
__global__ void pack_w_kernel(const float* __restrict__ w,
                              uint64_t* __restrict__ wp) {
    int gtid = blockIdx.x * blockDim.x + threadIdx.x;
    int wave = gtid >> 6, lane = gtid & 63;
    int nw = (gridDim.x * blockDim.x) >> 6;
    const int ntask = 9 * 2 * COUT;
    for (int t = wave; t < ntask; t += nw) {
        int oc = t & 255, hf = (t >> 8) & 1, tap = t >> 9;
        float v = w[((size_t)(tap * CIN + 2 * lane + hf)) * COUT + oc];
        uint64_t m = __ballot(v < 0.0f);
        if (lane == 0) wp[(size_t)(tap * 2 + hf) * COUT + oc] = m;
    }
}

__device__ __forceinline__ void tap2(const uint64_t c[2], const uint64_t w[2][2],
                                     int& a, int& b) {
    a += __popcll(c[0] ^ w[0][0]) + __popcll(c[1] ^ w[1][0]);
    b += __popcll(c[0] ^ w[0][1]) + __popcll(c[1] ^ w[1][1]);
}

__device__ __forceinline__ void popc9x2(const uint64_t X[3][2], const uint64_t Y[3][2],
                                        const uint64_t Z[3][2],
                                        const uint64_t wr[9][2][2], int& a, int& b) {
#pragma unroll
    for (int kh = 0; kh < 3; ++kh) {
        tap2(X[kh], wr[kh * 3 + 0], a, b);
        tap2(Y[kh], wr[kh * 3 + 1], a, b);
        tap2(Z[kh], wr[kh * 3 + 2], a, b);
    }
}

#define LOADCOL(dst, cc)                                        \
    do {                                                        \
        _Pragma("unroll")                                       \
        for (int _k = 0; _k < 3; ++_k) {                        \
            ulonglong2 _t = *(const ulonglong2*)xs[cc][g + _k]; \
            dst[_k][0] = _t.x; dst[_k][1] = _t.y;               \
        }                                                       \
    } while (0)

#define STEP(Xc, Yc, Zc, Kk)                                     \
    do {                                                         \
        int _a = 0, _b = 0;                                      \
        popc9x2(Xc, Yc, Zc, wr, _a, _b);                         \
        float2 _o;                                               \
        _o.x = (float)(Kk[0] - 2 * _a);                          \
        _o.y = (float)(Kk[1] - 2 * _b);                          \
        *(float2*)po = _o;                                       \
        po += COUT;                                              \
    } while (0)

// block = (n, h-pair); 256 thr = 2 row-groups x 128; thread -> oc {2q, 2q+1}
__global__ __launch_bounds__(256, 2) void bconv_kernel(
        const uint64_t* __restrict__ xp,
        const uint64_t* __restrict__ wp,
        float* __restrict__ out) {
    __shared__ alignas(16) uint64_t xs[58][4][2];  // [col+1][row h0-1+k][half]

    int bh = blockIdx.x % 28;
    int n  = blockIdx.x / 28;
    int h0 = bh * 2;
    int tid = threadIdx.x;
    int g = tid >> 7;            // row group: output row h = h0 + g
    int q = tid & 127;
    int oc0 = 2 * q;
    int h = h0 + g;

    // single-pass staging: each cell written exactly once (zero or data)
    for (int i = tid; i < 4 * 58; i += 256) {
        int row = i / 58, col = i % 58;
        int rr = h0 - 1 + row, cc = col - 1;
        uint64_t v0 = 0, v1 = 0;
        if ((unsigned)rr < IH && (unsigned)cc < IW) {
            const uint64_t* pp = xp + 2 * (((size_t)n * IH + rr) * IW + cc);
            v0 = pp[0]; v1 = pp[1];
        }
        xs[col][row][0] = v0; xs[col][row][1] = v1;
    }

    // filter: 9 taps x 2 halves x 2 oc = 36 u64 (dwordx4 loads, oc-adjacent)
    uint64_t wr[9][2][2];
#pragma unroll
    for (int t = 0; t < 9; ++t) {
#pragma unroll
        for (int hf = 0; hf < 2; ++hf) {
            ulonglong2 v = *(const ulonglong2*)&wp[(size_t)(t * 2 + hf) * COUT + oc0];
            wr[t][hf][0] = v.x; wr[t][hf][1] = v.y;
        }
    }
    __syncthreads();

    // edge-correction K constants per oc-sub
    int pc[2][9];
#pragma unroll
    for (int t = 0; t < 9; ++t) {
        pc[0][t] = __popcll(wr[t][0][0]) + __popcll(wr[t][1][0]);
        pc[1][t] = __popcll(wr[t][0][1]) + __popcll(wr[t][1][1]);
    }
    bool e0 = (h == 0), e2 = (h == IH - 1);
    int K0a[2], Kia[2], K55a[2];
#pragma unroll
    for (int s = 0; s < 2; ++s) {
        int rs0 = pc[s][0] + pc[s][1] + pc[s][2];
        int rs2 = pc[s][6] + pc[s][7] + pc[s][8];
        int cs0 = pc[s][0] + pc[s][3] + pc[s][6];
        int cs2 = pc[s][2] + pc[s][5] + pc[s][8];
        int vh  = 3 - (e0 ? 1 : 0) - (e2 ? 1 : 0);
        int inv = e0 ? rs0 : (e2 ? rs2 : 0);
        int c0  = e0 ? pc[s][0] : (e2 ? pc[s][6] : 0);
        int c2  = e0 ? pc[s][2] : (e2 ? pc[s][8] : 0);
        Kia[s]  = 384 * vh + 2 * inv;
        K0a[s]  = 256 * vh + 2 * (inv + cs0 - c0);
        K55a[s] = 256 * vh + 2 * (inv + cs2 - c2);
    }

    float* po = out + (((size_t)n * IH + h) * IW) * COUT + oc0;

    uint64_t A[3][2], B[3][2], C[3][2];
    LOADCOL(A, 0);
    LOADCOL(B, 1);
    LOADCOL(C, 2);
    STEP(A, B, C, K0a);          // w=0
    LOADCOL(A, 3);
    STEP(B, C, A, Kia);          // w=1
    for (int wb = 2; wb <= 53; wb += 3) {
        LOADCOL(B, wb + 2);
        STEP(C, A, B, Kia);
        LOADCOL(C, wb + 3);
        STEP(A, B, C, Kia);
        LOADCOL(A, wb + 4);
        if (wb == 53) { STEP(B, C, A, K55a); }
        else          { STEP(B, C, A, Kia); }
    }
}

extern "C" void kernel_launch(void* const* d_in, const int* in_sizes, int n_in,
                              void* d_out, int out_size, void* d_ws, size_t ws_size,
                              hipStream_t stream) {
    const float* x = (const float*)d_in[0];
    const float* w = (const float*)d_in[1];
    float* out = (float*)d_out;

    uint64_t* wp = (uint64_t*)d_ws;                       // 36 KB
    uint64_t* xp = (uint64_t*)((char*)d_ws + (64 << 10)); // 3.2 MB

    const int npix = NB * IH * IW;   // 200704

    pack_x_kernel<<<6272, 256, 0, stream>>>(x, xp, npix);  // 25088 waves, 8 it
    pack_w_kernel<<<288, 256, 0, stream>>>(w, wp);
    bconv_kernel<<<NB * 28, 256, 0, stream>>>(xp, wp, out);
}